// Round 20
// baseline (508.106 us; speedup 1.0000x reference)
//
#include <hip/hip_runtime.h>

// PolicyNetGARCH: B=1024 S=512 OBS=5 NINS=2 H=32 NBLK=4
// Round 20: R19's M-split (2 waves per stage, split by gate rows; 512 waves
// = 2/SIMD over all 64 CUs) with the R19 correctness bug fixed:
// the cross-wave RMS partial (ss) and head partials (pa/pb) are PER BATCH
// COLUMN b (16 values), not wave-uniform scalars. R19 published lane==0's
// value only -> every column consumed column 0's partner partial
// (absmax 0.27). Now ssbuf/headbuf are [..][16], written by the g==0 lanes
// (lane==b) and read indexed by b. Everything else unchanged from R19:
// verified MFMA datapath (C/D==B-fragment), skewed 4-stage pipeline, SUP=4,
// parity-dbuf xslot, depth-2 hv ring with monotonic flag tags, hoisted
// x-side, exp2-domain fused activations.

constexpr int B_ = 1024, S_ = 512, OBS_ = 5, NINS_ = 2, H_ = 32, NBLK_ = 4;
constexpr int SUP_ = 4;
constexpr int TT_ = S_ / SUP_;
constexpr float EPS_ = 1e-6f;
constexpr float LOG2E_ = 1.4426950408889634f;

typedef __fp16 h2 __attribute__((ext_vector_type(2)));
typedef __fp16 h8 __attribute__((ext_vector_type(8)));
typedef float  f4 __attribute__((ext_vector_type(4)));
typedef int    i4 __attribute__((ext_vector_type(4)));

__device__ __forceinline__ float rcp_(float x) { return __builtin_amdgcn_rcpf(x); }
__device__ __forceinline__ float rsq_(float x) { return __builtin_amdgcn_rsqf(x); }
__device__ __forceinline__ float ex2_(float x) { return __builtin_amdgcn_exp2f(x); }
__device__ __forceinline__ h2 pk_(float a, float b) {
  return __builtin_amdgcn_cvt_pkrtz(a, b);
}
__device__ __forceinline__ h8 pk8_(f4 lo, f4 hi) {
  i4 q;
  q[0] = __builtin_bit_cast(int, pk_(lo[0], lo[1]));
  q[1] = __builtin_bit_cast(int, pk_(lo[2], lo[3]));
  q[2] = __builtin_bit_cast(int, pk_(hi[0], hi[1]));
  q[3] = __builtin_bit_cast(int, pk_(hi[2], hi[3]));
  return __builtin_bit_cast(h8, q);
}
__device__ __forceinline__ f4 mfma_(h8 a, h8 b, f4 c) {
  return __builtin_amdgcn_mfma_f32_16x16x32_f16(a, b, c, 0, 0, 0);
}
__device__ __forceinline__ f4 e4n_(f4 a) {
  f4 r;
  r[0] = ex2_(-a[0]); r[1] = ex2_(-a[1]);
  r[2] = ex2_(-a[2]); r[3] = ex2_(-a[3]);
  return r;
}
__device__ __forceinline__ f4 rcp4_(f4 a) {
  f4 r;
  r[0] = rcp_(a[0]); r[1] = rcp_(a[1]);
  r[2] = rcp_(a[2]); r[3] = rcp_(a[3]);
  return r;
}
__device__ __forceinline__ float dot4_(f4 a, f4 x) {
  float s = a[0] * x[0];
  s = fmaf(a[1], x[1], s);
  s = fmaf(a[2], x[2], s);
  s = fmaf(a[3], x[3], s);
  return s;
}
__device__ __forceinline__ float psw16_(float v, bool re) {
#if __has_builtin(__builtin_amdgcn_permlane16_swap)
  auto r = __builtin_amdgcn_permlane16_swap(
      __builtin_bit_cast(int, v), __builtin_bit_cast(int, v), false, false);
  return __builtin_bit_cast(float, re ? (int)r[1] : (int)r[0]);
#else
  return __shfl_xor(v, 16);
#endif
}
__device__ __forceinline__ float psw32_(float v, bool lo) {
#if __has_builtin(__builtin_amdgcn_permlane32_swap)
  auto r = __builtin_amdgcn_permlane32_swap(
      __builtin_bit_cast(int, v), __builtin_bit_cast(int, v), false, false);
  return __builtin_bit_cast(float, lo ? (int)r[1] : (int)r[0]);
#else
  return __shfl_xor(v, 32);
#endif
}
__device__ __forceinline__ void flag_st_(int* p, int v) {
  __threadfence_block();
  __hip_atomic_store(p, v, __ATOMIC_RELAXED, __HIP_MEMORY_SCOPE_WORKGROUP);
}
__device__ __forceinline__ void flag_wait_(int* p, int v) {
  while (__hip_atomic_load(p, __ATOMIC_RELAXED, __HIP_MEMORY_SCOPE_WORKGROUP) < v) {}
  __threadfence_block();
}

// fused single-tile activations (exp2 domain, single-rcp gate path)
#define ACT1(GI, GF, GG, GO) do {                                          \
    const f4 _one = {1.f, 1.f, 1.f, 1.f};                                  \
    const f4 _Ei = e4n_(GI);                                               \
    const f4 _Eg = e4n_(GG);                                               \
    const f4 _Ef = e4n_(GF);                                               \
    const f4 _a = (_one + _Ei) * (_one + _Eg);                             \
    const f4 _f = _one + _Ef;                                              \
    const f4 _r = rcp4_(_a * _f);                                          \
    const f4 _sitg = (_one - _Eg) * _f * _r;                               \
    const f4 _sf = _a * _r;                                                \
    c_own = _sf * c_own + _sitg;                                           \
    const f4 _Eo = e4n_(GO);                                               \
    const f4 _Ec = e4n_(c_own * (2.f * LOG2E_));                           \
    hv_own = (_one - _Ec) * rcp4_((_one + _Eo) * (_one + _Ec));            \
  } while (0)

__global__ __launch_bounds__(512, 1) void garch_msplit2_kernel(
    const float* __restrict__ obs, const float* __restrict__ prev,
    const float* __restrict__ W_in, const float* __restrict__ b_in,
    const float* __restrict__ rms_w,
    const float* __restrict__ W_ih, const float* __restrict__ W_hh,
    const float* __restrict__ b_ih, const float* __restrict__ b_hh,
    const float* __restrict__ head_w, const float* __restrict__ head_b,
    float* __restrict__ out) {
  const int tid  = threadIdx.x;
  const int w    = tid >> 6;
  const int k    = w & 3;           // LSTM block (pipeline stage)
  const int hf   = w >> 2;          // M-half: 0 = h-units 0-15, 1 = 16-31
  const int lane = tid & 63;
  const int g    = lane >> 4;
  const int b    = lane & 15;
  const int bg   = blockIdx.x * 16 + b;
  const bool re_ = ((lane >> 4) & 1) == 0;
  const bool lo_ = (lane < 32);

  __shared__ __align__(16) float xslot[3][2][SUP_][16][36];
  __shared__ int   xnbuf[4][2][SUP_][64][2];
  __shared__ int   hvbuf[4][2][2][64][2];
  __shared__ float ssbuf[4][2][SUP_][16];     // per batch column!
  __shared__ float headbuf[2][SUP_][16];      // per batch column!
  __shared__ int   xnflag[4][2];
  __shared__ int   hvflag[4][2];
  __shared__ int   headflag;

  // init flags + hv ring (initial h-state = 0)
  for (int i = tid; i < 4 * 2 * 2 * 64 * 2; i += 512) ((int*)hvbuf)[i] = 0;
  if (tid < 8) { xnflag[tid >> 1][tid & 1] = 0; hvflag[tid >> 1][tid & 1] = 0; }
  if (tid == 8) headflag = 0;

  // ---- weights: this wave's 4 m-tiles (m = 2l + hf); exp2-prescaled ----
  h8 wx[4], wh[4];
  f4 biasv[4];
  {
    const size_t wb = (size_t)k * 128 * 32;
#pragma unroll
    for (int l = 0; l < 4; ++l) {
      const int m = 2 * l + hf;                 // l: 0=i 1=f 2=g 3=o
      const float scl = (l == 2) ? 2.f * LOG2E_ : LOG2E_;
      const int row = 16 * m + b;
      const float* px = W_ih + wb + (size_t)row * 32;
      f4 x0 = *(const f4*)(px + 4 * g);
      f4 x1 = *(const f4*)(px + 16 + 4 * g);
      wx[l] = pk8_(x0 * scl, x1 * scl);
      const float* ph = W_hh + wb + (size_t)row * 32;
      f4 h0v = *(const f4*)(ph + 4 * g);
      f4 h1v = *(const f4*)(ph + 16 + 4 * g);
      wh[l] = pk8_(h0v * scl, h1v * scl);
      f4 bv;
#pragma unroll
      for (int r = 0; r < 4; ++r) {
        const int gr = k * 128 + 16 * m + 4 * g + r;
        bv[r] = (b_ih[gr] + b_hh[gr]) * scl;
      }
      biasv[l] = bv;
    }
  }
  f4 rwv;
#pragma unroll
  for (int r = 0; r < 4; ++r) rwv[r] = rms_w[k * 32 + 16 * hf + 4 * g + r];

  // ---- role constants ----
  h8 win = {};
  f4 binv = {};
  const float* obs_b = nullptr; const float* prev_b = nullptr;
  f4 cin[SUP_] = {}, nin[SUP_] = {};
  if (k == 0) {
    f4 lw; const f4 z = {};
#pragma unroll
    for (int r = 0; r < 4; ++r) {
      const int kk = 4 * g + r;
      lw[r] = (kk < 7) ? W_in[(size_t)(16 * hf + b) * 7 + kk] : 0.f;
    }
    win = pk8_(lw, z);
#pragma unroll
    for (int r = 0; r < 4; ++r) binv[r] = b_in[16 * hf + 4 * g + r];
    obs_b  = obs  + (size_t)bg * S_ * OBS_;
    prev_b = prev + (size_t)bg * S_ * NINS_;
#pragma unroll
    for (int s = 0; s < SUP_; ++s) {
      const float* o = obs_b + (size_t)s * OBS_;
      if (g == 0)      { cin[s][0] = o[0]; cin[s][1] = o[1]; cin[s][2] = o[2]; cin[s][3] = o[3]; }
      else if (g == 1) { cin[s][0] = o[4]; cin[s][1] = prev_b[2 * s]; cin[s][2] = prev_b[2 * s + 1]; cin[s][3] = 0.f; }
    }
  }
  f4 hwa = {}, hwb = {};
  float hb0 = 0.f, hb1 = 0.f;
  if (k == 3) {
#pragma unroll
    for (int r = 0; r < 4; ++r) {
      hwa[r] = head_w[16 * hf + 4 * g + r]      * LOG2E_;   // out0, own rows
      hwb[r] = head_w[32 + 16 * hf + 4 * g + r] * LOG2E_;   // out1, own rows
    }
    hb0 = head_b[0] * LOG2E_;
    hb1 = head_b[1] * LOG2E_;
  }

  f4 c_own = {}, hv_own = {};
  int hvpk0 = 0, hvpk1 = 0;

  float* out_y  = out;                                // [2][B][S]
  float* out_hT = out + (size_t)NINS_ * B_ * S_;      // [4][B][H]
  float* out_cT = out_hT + (size_t)NBLK_ * B_ * H_;   // [4][B][H]

  for (int tau = 0; tau < TT_ + NBLK_ - 1; ++tau) {
    __syncthreads();
    const int tt = tau - k;
    if (tt < 0 || tt >= TT_) continue;
    const int t0 = SUP_ * tt;
    const int wp = tau & 1, rp = (tau + 1) & 1;

    // ---- 1. own xt half-tiles for SUP_ steps ----
    f4 xt[SUP_];
    if (k == 0) {
      if (tt + 1 < TT_) {
#pragma unroll
        for (int s = 0; s < SUP_; ++s) {
          const int t = t0 + SUP_ + s;
          const float* o = obs_b + (size_t)t * OBS_;
          if (g == 0)      { nin[s][0] = o[0]; nin[s][1] = o[1]; nin[s][2] = o[2]; nin[s][3] = o[3]; }
          else if (g == 1) { nin[s][0] = o[4]; nin[s][1] = prev_b[2 * t]; nin[s][2] = prev_b[2 * t + 1]; nin[s][3] = 0.f; }
        }
      }
      const f4 z = {};
#pragma unroll
      for (int s = 0; s < SUP_; ++s) {
        const h8 binp = pk8_(cin[s], z);
        xt[s] = mfma_(win, binp, binv);
      }
    } else {
#pragma unroll
      for (int s = 0; s < SUP_; ++s)
        xt[s] = *(const f4*)&xslot[k - 1][rp][s][b][16 * hf + 4 * g];
    }

    // ---- 2. x-side: publish xn halves + per-b RMS partials ----
    int xnp0[SUP_], xnp1[SUP_];
    float ssp[SUP_];
#pragma unroll
    for (int s = 0; s < SUP_; ++s) {
      const f4 xn = xt[s] * rwv;
      xnp0[s] = __builtin_bit_cast(int, pk_(xn[0], xn[1]));
      xnp1[s] = __builtin_bit_cast(int, pk_(xn[2], xn[3]));
      float ss = dot4_(xt[s], xt[s]);
      ss += psw16_(ss, re_);
      ss += psw32_(ss, lo_);
      ssp[s] = ss;                      // uniform over g, varies with b
      int* p = &xnbuf[k][hf][s][lane][0];
      p[0] = xnp0[s]; p[1] = xnp1[s];
      if (lane < 16) ssbuf[k][hf][s][lane] = ss;   // lane==b for g==0
    }
    flag_st_(&xnflag[k][hf], tt + 1);
    flag_wait_(&xnflag[k][hf ^ 1], tt + 1);

    float rinv[SUP_];
    h8 bx[SUP_];
#pragma unroll
    for (int s = 0; s < SUP_; ++s) {
      const int* p = &xnbuf[k][hf ^ 1][s][lane][0];
      const int o0 = p[0], o1 = p[1];
      i4 q;
      if (hf == 0) { q[0] = xnp0[s]; q[1] = xnp1[s]; q[2] = o0; q[3] = o1; }
      else         { q[0] = o0; q[1] = o1; q[2] = xnp0[s]; q[3] = xnp1[s]; }
      bx[s] = __builtin_bit_cast(h8, q);
      const float ss = ssp[s] + ssbuf[k][hf ^ 1][s][b];
      rinv[s] = rsq_(ss * (1.0f / 32.0f) + EPS_);
    }
    f4 gx[SUP_][4];
    const f4 z4 = {};
#pragma unroll
    for (int s = 0; s < SUP_; ++s) {
#pragma unroll
      for (int l = 0; l < 4; ++l) gx[s][l] = mfma_(wx[l], bx[s], z4);
    }

    // ---- 3. serial h-chain with per-step hv handshake ----
#pragma unroll
    for (int s = 0; s < SUP_; ++s) {
      const int gs = tt * SUP_ + s + 1;
      flag_wait_(&hvflag[k][hf ^ 1], gs - 1);
      const int* hp = &hvbuf[k][hf ^ 1][(gs - 1) & 1][lane][0];
      const int ho0 = hp[0], ho1 = hp[1];
      i4 qh;
      if (hf == 0) { qh[0] = hvpk0; qh[1] = hvpk1; qh[2] = ho0; qh[3] = ho1; }
      else         { qh[0] = ho0; qh[1] = ho1; qh[2] = hvpk0; qh[3] = hvpk1; }
      const h8 bh = __builtin_bit_cast(h8, qh);
      const f4 g0 = gx[s][0] * rinv[s] + mfma_(wh[0], bh, biasv[0]);
      const f4 g1 = gx[s][1] * rinv[s] + mfma_(wh[1], bh, biasv[1]);
      const f4 g2 = gx[s][2] * rinv[s] + mfma_(wh[2], bh, biasv[2]);
      const f4 g3 = gx[s][3] * rinv[s] + mfma_(wh[3], bh, biasv[3]);
      ACT1(g0, g1, g2, g3);             // updates c_own, hv_own
      xt[s] += hv_own;
      hvpk0 = __builtin_bit_cast(int, pk_(hv_own[0], hv_own[1]));
      hvpk1 = __builtin_bit_cast(int, pk_(hv_own[2], hv_own[3]));
      int* hq = &hvbuf[k][hf][gs & 1][lane][0];
      hq[0] = hvpk0; hq[1] = hvpk1;
      flag_st_(&hvflag[k][hf], gs);
    }

    // ---- 4. handoff / head ----
    if (k < 3) {
#pragma unroll
      for (int s = 0; s < SUP_; ++s)
        *(f4*)&xslot[k][wp][s][b][16 * hf + 4 * g] = xt[s];
    } else {
      float pa[SUP_], pb[SUP_];
#pragma unroll
      for (int s = 0; s < SUP_; ++s) {
        float a = dot4_(hwa, xt[s]);
        float bb = dot4_(hwb, xt[s]);
        a += psw16_(a, re_);  a += psw32_(a, lo_);
        bb += psw16_(bb, re_); bb += psw32_(bb, lo_);
        pa[s] = a; pb[s] = bb;          // per-b, uniform over g
      }
      if (hf == 0) {
        if (lane < 16) {
#pragma unroll
          for (int s = 0; s < SUP_; ++s) {
            headbuf[0][s][lane] = pa[s];
            headbuf[1][s][lane] = pb[s];
          }
        }
        flag_st_(&headflag, tt + 1);
      } else {
        flag_wait_(&headflag, tt + 1);
        if (lane < 16) {
          f4 v0, v1;
#pragma unroll
          for (int s = 0; s < SUP_; ++s) {
            const float p0 = pa[s] + headbuf[0][s][lane] + hb0;
            const float p1 = pb[s] + headbuf[1][s][lane] + hb1;
            v0[s] = copysignf(fminf(ex2_(fabsf(p0)) - 1.f, 5.f),  p0);
            v1[s] = copysignf(fminf(ex2_(fabsf(p1)) - 1.f, 10.f), p1);
          }
          *(f4*)&out_y[(size_t)bg * S_ + t0]                   = v0;
          *(f4*)&out_y[(size_t)B_ * S_ + (size_t)bg * S_ + t0] = v1;
        }
      }
    }

    // ---- 5. final states (own half rows) ----
    if (tt == TT_ - 1) {
      float* hp = out_hT + ((size_t)k * B_ + bg) * H_;
      float* cp = out_cT + ((size_t)k * B_ + bg) * H_;
#pragma unroll
      for (int r = 0; r < 4; ++r) {
        hp[16 * hf + 4 * g + r] = hv_own[r];
        cp[16 * hf + 4 * g + r] = c_own[r];
      }
    }

    if (k == 0) {
#pragma unroll
      for (int s = 0; s < SUP_; ++s) cin[s] = nin[s];
    }
  }
}

extern "C" void kernel_launch(void* const* d_in, const int* in_sizes, int n_in,
                              void* d_out, int out_size, void* d_ws, size_t ws_size,
                              hipStream_t stream) {
  (void)in_sizes; (void)n_in; (void)d_ws; (void)ws_size; (void)out_size;
  garch_msplit2_kernel<<<dim3(B_ / 16), dim3(512), 0, stream>>>(
      (const float*)d_in[0],  // obs_sequence [B,S,OBS]
      (const float*)d_in[1],  // prev_actions [B,S,NINS]
      (const float*)d_in[2],  // W_in [H, OBS+NINS]
      (const float*)d_in[3],  // b_in [H]
      (const float*)d_in[4],  // rms_w [NBLK,H]
      (const float*)d_in[5],  // W_ih [NBLK,4H,H]
      (const float*)d_in[6],  // W_hh [NBLK,4H,H]
      (const float*)d_in[7],  // b_ih [NBLK,4H]
      (const float*)d_in[8],  // b_hh [NBLK,4H]
      (const float*)d_in[9],  // head_w [NINS,H]
      (const float*)d_in[10], // head_b [NINS]
      (float*)d_out);
}

// Round 21
// 426.986 us; speedup vs baseline: 1.1900x; 1.1900x over previous
//
#include <hip/hip_runtime.h>

// PolicyNetGARCH: B=1024 S=512 OBS=5 NINS=2 H=32 NBLK=4
// Round 21: REVERT to R18 (best measured: 424 us), declared practical floor
// of the explored design space.
// Structure: 64 WGs x 4 stage-waves (wave k = LSTM block k), skewed
// pipeline, SUP=8 timesteps per barrier processed as 2 phases of 4 (keeps
// register live-set bounded), parity-dbuf LDS xt handoff, permlane16/32
// reduces, hoisted x-side (RMS + rinv-folded packs + x-MFMAs), serial
// h-chain of 8 h-MFMAs with bias-carrying C operand, single-rcp fused
// exp2-domain activations, verified MFMA C/D==B-fragment feedback.
// Rationale for stopping here: 512-step serial scan; widest verified
// decomposition = 64 column-tiles x 4 stages = 1 wave/SIMD on 64 CUs;
// per-step chain ~2000cy at ~55% per-CU issue occupancy. R14/R15 (ILP/
// co-located pipelines) halved active CUs; R19/R20 (M-split TLP) injected
// handshake latency into the recurrence (508us >= 424us threshold).

constexpr int B_ = 1024, S_ = 512, OBS_ = 5, NINS_ = 2, H_ = 32, NBLK_ = 4;
constexpr int SUP_ = 8;           // timesteps per barrier
constexpr int PH_  = 4;           // steps per phase (2 phases per barrier)
constexpr int TT_ = S_ / SUP_;    // super-ticks = 64
constexpr float EPS_ = 1e-6f;
constexpr float LOG2E_ = 1.4426950408889634f;

typedef __fp16 h2 __attribute__((ext_vector_type(2)));
typedef __fp16 h8 __attribute__((ext_vector_type(8)));
typedef float  f4 __attribute__((ext_vector_type(4)));
typedef int    i4 __attribute__((ext_vector_type(4)));

__device__ __forceinline__ float rcp_(float x) { return __builtin_amdgcn_rcpf(x); }
__device__ __forceinline__ float rsq_(float x) { return __builtin_amdgcn_rsqf(x); }
__device__ __forceinline__ float ex2_(float x) { return __builtin_amdgcn_exp2f(x); }
__device__ __forceinline__ h2 pk_(float a, float b) {
  return __builtin_amdgcn_cvt_pkrtz(a, b);
}
__device__ __forceinline__ h8 pk8_(f4 lo, f4 hi) {
  i4 q;
  q[0] = __builtin_bit_cast(int, pk_(lo[0], lo[1]));
  q[1] = __builtin_bit_cast(int, pk_(lo[2], lo[3]));
  q[2] = __builtin_bit_cast(int, pk_(hi[0], hi[1]));
  q[3] = __builtin_bit_cast(int, pk_(hi[2], hi[3]));
  return __builtin_bit_cast(h8, q);
}
__device__ __forceinline__ f4 mfma_(h8 a, h8 b, f4 c) {
  return __builtin_amdgcn_mfma_f32_16x16x32_f16(a, b, c, 0, 0, 0);
}
__device__ __forceinline__ f4 e4n_(f4 a) {          // ex2(-a) elementwise
  f4 r;
  r[0] = ex2_(-a[0]); r[1] = ex2_(-a[1]);
  r[2] = ex2_(-a[2]); r[3] = ex2_(-a[3]);
  return r;
}
__device__ __forceinline__ f4 rcp4_(f4 a) {
  f4 r;
  r[0] = rcp_(a[0]); r[1] = rcp_(a[1]);
  r[2] = rcp_(a[2]); r[3] = rcp_(a[3]);
  return r;
}
__device__ __forceinline__ float dot44_(f4 a, f4 x, f4 b2, f4 y) {
  float s = a[0] * x[0];
  s = fmaf(a[1], x[1], s); s = fmaf(a[2], x[2], s); s = fmaf(a[3], x[3], s);
  s = fmaf(b2[0], y[0], s); s = fmaf(b2[1], y[1], s);
  s = fmaf(b2[2], y[2], s); s = fmaf(b2[3], y[3], s);
  return s;
}
// partner across lane^16 (VALU permlane; re = even 16-row)
__device__ __forceinline__ float psw16_(float v, bool re) {
#if __has_builtin(__builtin_amdgcn_permlane16_swap)
  auto r = __builtin_amdgcn_permlane16_swap(
      __builtin_bit_cast(int, v), __builtin_bit_cast(int, v), false, false);
  return __builtin_bit_cast(float, re ? (int)r[1] : (int)r[0]);
#else
  return __shfl_xor(v, 16);
#endif
}
// partner across lane^32 (VALU permlane; lo = lane<32)
__device__ __forceinline__ float psw32_(float v, bool lo) {
#if __has_builtin(__builtin_amdgcn_permlane32_swap)
  auto r = __builtin_amdgcn_permlane32_swap(
      __builtin_bit_cast(int, v), __builtin_bit_cast(int, v), false, false);
  return __builtin_bit_cast(float, lo ? (int)r[1] : (int)r[0]);
#else
  return __shfl_xor(v, 32);
#endif
}

// Fused activations (single-rcp gate path): updates C and HV.
// sitg=(1-Eg)(1+Ef)r, sf=(1+Ei)(1+Eg)r with r=rcp((1+Ei)(1+Eg)(1+Ef));
// h=(1-Ec)*rcp((1+Eo)(1+Ec)).
#define ACT_TILE(GI, GF, GG, GO, C, HV) do {                               \
    const f4 _one = {1.f, 1.f, 1.f, 1.f};                                  \
    const f4 _Ei = e4n_(GI);                                               \
    const f4 _Eg = e4n_(GG);                                               \
    const f4 _Ef = e4n_(GF);                                               \
    const f4 _a = (_one + _Ei) * (_one + _Eg);                             \
    const f4 _f = _one + _Ef;                                              \
    const f4 _r = rcp4_(_a * _f);                                          \
    const f4 _sitg = (_one - _Eg) * _f * _r;                               \
    const f4 _sf = _a * _r;                                                \
    (C) = _sf * (C) + _sitg;                                               \
    const f4 _Eo = e4n_(GO);                                               \
    const f4 _Ec = e4n_((C) * (2.f * LOG2E_));                             \
    (HV) = (_one - _Ec) * rcp4_((_one + _Eo) * (_one + _Ec));              \
  } while (0)

__global__ __launch_bounds__(256, 1) void garch_mfma8_kernel(
    const float* __restrict__ obs, const float* __restrict__ prev,
    const float* __restrict__ W_in, const float* __restrict__ b_in,
    const float* __restrict__ rms_w,
    const float* __restrict__ W_ih, const float* __restrict__ W_hh,
    const float* __restrict__ b_ih, const float* __restrict__ b_hh,
    const float* __restrict__ head_w, const float* __restrict__ head_b,
    float* __restrict__ out) {
  const int tid  = threadIdx.x;
  const int k    = tid >> 6;        // wave role == LSTM block
  const int lane = tid & 63;
  const int g    = lane >> 4;       // k-chunk / row group
  const int b    = lane & 15;       // batch column within tile
  const int bg   = blockIdx.x * 16 + b;
  const bool re_ = ((lane >> 4) & 1) == 0;
  const bool lo_ = (lane < 32);

  // xt handoff: [stage][parity][step][bcol][32 rows + pad] = 110592 B
  __shared__ __align__(16) float xslot[3][2][SUP_][16][36];

  // ---- A-fragments / biases for this wave's block (exp2-prescaled) ----
  h8 wx[8], wh[8];
  f4 biasv[8];
  {
    const size_t wb = (size_t)k * 128 * 32;
#pragma unroll
    for (int mi = 0; mi < 8; ++mi) {
      const float scl = (mi == 4 || mi == 5) ? 2.f * LOG2E_ : LOG2E_;
      const int row = 16 * mi + b;
      const float* px = W_ih + wb + (size_t)row * 32;
      f4 x0 = *(const f4*)(px + 4 * g);
      f4 x1 = *(const f4*)(px + 16 + 4 * g);
      wx[mi] = pk8_(x0 * scl, x1 * scl);
      const float* ph = W_hh + wb + (size_t)row * 32;
      f4 h0v = *(const f4*)(ph + 4 * g);
      f4 h1v = *(const f4*)(ph + 16 + 4 * g);
      wh[mi] = pk8_(h0v * scl, h1v * scl);
      f4 bv;
#pragma unroll
      for (int r = 0; r < 4; ++r) {
        const int gr = k * 128 + 16 * mi + 4 * g + r;
        bv[r] = (b_ih[gr] + b_hh[gr]) * scl;
      }
      biasv[mi] = bv;
    }
  }
  f4 rw0v, rw1v;
#pragma unroll
  for (int r = 0; r < 4; ++r) {
    rw0v[r] = rms_w[k * 32 + 4 * g + r];
    rw1v[r] = rms_w[k * 32 + 16 + 4 * g + r];
  }

  // ---- role-specific constants ----
  h8 winA0 = {}, winA1 = {};
  f4 bin0v = {}, bin1v = {};
  const float* obs_b = nullptr; const float* prev_b = nullptr;
  f4 cin[SUP_] = {};                // per-step inputs (this lane's 4 vals)
  if (k == 0) {
    f4 lo0, lo1; const f4 z = {};
#pragma unroll
    for (int r = 0; r < 4; ++r) {
      const int kk = 4 * g + r;
      lo0[r] = (kk < 7) ? W_in[(size_t)b * 7 + kk] : 0.f;
      lo1[r] = (kk < 7) ? W_in[(size_t)(16 + b) * 7 + kk] : 0.f;
    }
    winA0 = pk8_(lo0, z);
    winA1 = pk8_(lo1, z);
#pragma unroll
    for (int r = 0; r < 4; ++r) {
      bin0v[r] = b_in[4 * g + r];
      bin1v[r] = b_in[16 + 4 * g + r];
    }
    obs_b  = obs  + (size_t)bg * S_ * OBS_;
    prev_b = prev + (size_t)bg * S_ * NINS_;
#pragma unroll
    for (int s = 0; s < SUP_; ++s) {
      const float* o = obs_b + (size_t)s * OBS_;
      if (g == 0)      { cin[s][0] = o[0]; cin[s][1] = o[1]; cin[s][2] = o[2]; cin[s][3] = o[3]; }
      else if (g == 1) { cin[s][0] = o[4]; cin[s][1] = prev_b[2 * s]; cin[s][2] = prev_b[2 * s + 1]; cin[s][3] = 0.f; }
    }
  }
  f4 hw00 = {}, hw01 = {}, hw10 = {}, hw11 = {};
  float hb0 = 0.f, hb1 = 0.f;
  if (k == 3) {
#pragma unroll
    for (int r = 0; r < 4; ++r) {
      hw00[r] = head_w[4 * g + r]      * LOG2E_;
      hw01[r] = head_w[16 + 4 * g + r] * LOG2E_;
      hw10[r] = head_w[32 + 4 * g + r] * LOG2E_;
      hw11[r] = head_w[48 + 4 * g + r] * LOG2E_;
    }
    hb0 = head_b[0] * LOG2E_;
    hb1 = head_b[1] * LOG2E_;
  }

  // block state
  f4 c0 = {}, c1 = {}, hv0 = {}, hv1 = {};

  float* out_y  = out;                                // [2][B][S]
  float* out_hT = out + (size_t)NINS_ * B_ * S_;      // [4][B][H]
  float* out_cT = out_hT + (size_t)NBLK_ * B_ * H_;   // [4][B][H]

  for (int tau = 0; tau < TT_ + NBLK_ - 1; ++tau) {
    __syncthreads();
    const int tt = tau - k;           // wave-uniform super-tick window
    if (tt < 0 || tt >= TT_) continue;
    const int t0 = SUP_ * tt;
    const int wp = tau & 1, rp = (tau + 1) & 1;

#pragma unroll
    for (int p = 0; p < SUP_ / PH_; ++p) {
      // ---- 1. xt tiles for this phase's PH_ timesteps ----
      f4 x0[PH_], x1[PH_];
      if (k == 0) {
        const f4 z = {};
#pragma unroll
        for (int s = 0; s < PH_; ++s) {
          const int sg_ = p * PH_ + s;
          const h8 binp = pk8_(cin[sg_], z);   // g>=2 lanes: zeros
          x0[s] = mfma_(winA0, binp, bin0v);
          x1[s] = mfma_(winA1, binp, bin1v);
        }
        if (tt + 1 < TT_) {           // reload consumed inputs (next super-tick)
#pragma unroll
          for (int s = 0; s < PH_; ++s) {
            const int sg_ = p * PH_ + s;
            const int t = t0 + SUP_ + sg_;
            const float* o = obs_b + (size_t)t * OBS_;
            if (g == 0)      { cin[sg_][0] = o[0]; cin[sg_][1] = o[1]; cin[sg_][2] = o[2]; cin[sg_][3] = o[3]; }
            else if (g == 1) { cin[sg_][0] = o[4]; cin[sg_][1] = prev_b[2 * t]; cin[sg_][2] = prev_b[2 * t + 1]; cin[sg_][3] = 0.f; }
          }
        }
      } else {
#pragma unroll
        for (int s = 0; s < PH_; ++s) {
          const int sg_ = p * PH_ + s;
          x0[s] = *(const f4*)&xslot[k - 1][rp][sg_][b][4 * g];
          x1[s] = *(const f4*)&xslot[k - 1][rp][sg_][b][16 + 4 * g];
        }
      }

      // ---- 2a. HOISTED x-side: reduces + packs + 32 x-MFMAs ----
      h8 bx[PH_];
#pragma unroll
      for (int s = 0; s < PH_; ++s) {
        float ss = dot44_(x0[s], x0[s], x1[s], x1[s]);
        ss += psw16_(ss, re_);
        ss += psw32_(ss, lo_);
        const float rinv = rsq_(ss * (1.0f / 32.0f) + EPS_);
        bx[s] = pk8_(x0[s] * (rw0v * rinv), x1[s] * (rw1v * rinv));
      }
      f4 gx[PH_][8];
#pragma unroll
      for (int s = 0; s < PH_; ++s) {
#pragma unroll
        for (int m = 0; m < 8; ++m) {
          gx[s][m] = mfma_(wx[m], bx[s], biasv[m]);
        }
      }

      // ---- 2b. serial h-chain ----
#pragma unroll
      for (int s = 0; s < PH_; ++s) {
        const h8 bh = pk8_(hv0, hv1);
        const f4 gi0 = mfma_(wh[0], bh, gx[s][0]);
        const f4 gi1 = mfma_(wh[1], bh, gx[s][1]);
        const f4 gf0 = mfma_(wh[2], bh, gx[s][2]);
        const f4 gf1 = mfma_(wh[3], bh, gx[s][3]);
        const f4 gg0 = mfma_(wh[4], bh, gx[s][4]);
        const f4 gg1 = mfma_(wh[5], bh, gx[s][5]);
        const f4 go0 = mfma_(wh[6], bh, gx[s][6]);
        const f4 go1 = mfma_(wh[7], bh, gx[s][7]);
        ACT_TILE(gi0, gf0, gg0, go0, c0, hv0);
        ACT_TILE(gi1, gf1, gg1, go1, c1, hv1);
        x0[s] += hv0;
        x1[s] += hv1;
      }

      // ---- 3. handoff or head for this phase ----
      if (k < 3) {
#pragma unroll
        for (int s = 0; s < PH_; ++s) {
          const int sg_ = p * PH_ + s;
          *(f4*)&xslot[k][wp][sg_][b][4 * g]      = x0[s];
          *(f4*)&xslot[k][wp][sg_][b][16 + 4 * g] = x1[s];
        }
      } else {
        float p0[PH_], p1[PH_];
#pragma unroll
        for (int s = 0; s < PH_; ++s) {
          float a = dot44_(hw00, x0[s], hw01, x1[s]);
          float bq = dot44_(hw10, x0[s], hw11, x1[s]);
          a += psw16_(a, re_); a += psw32_(a, lo_);
          bq += psw16_(bq, re_); bq += psw32_(bq, lo_);
          p0[s] = a + hb0;
          p1[s] = bq + hb1;
        }
        if (lane < 16) {
          f4 v0, v1;
#pragma unroll
          for (int s = 0; s < PH_; ++s) {
            v0[s] = copysignf(fminf(ex2_(fabsf(p0[s])) - 1.f, 5.f),  p0[s]);
            v1[s] = copysignf(fminf(ex2_(fabsf(p1[s])) - 1.f, 10.f), p1[s]);
          }
          *(f4*)&out_y[(size_t)bg * S_ + t0 + p * PH_]                   = v0;
          *(f4*)&out_y[(size_t)B_ * S_ + (size_t)bg * S_ + t0 + p * PH_] = v1;
        }
      }
    }

    // ---- 4. final states ----
    if (tt == TT_ - 1) {
      float* hp = out_hT + ((size_t)k * B_ + bg) * H_;
      float* cp = out_cT + ((size_t)k * B_ + bg) * H_;
#pragma unroll
      for (int r = 0; r < 4; ++r) {
        hp[4 * g + r]      = hv0[r];
        hp[16 + 4 * g + r] = hv1[r];
        cp[4 * g + r]      = c0[r];
        cp[16 + 4 * g + r] = c1[r];
      }
    }
  }
}

extern "C" void kernel_launch(void* const* d_in, const int* in_sizes, int n_in,
                              void* d_out, int out_size, void* d_ws, size_t ws_size,
                              hipStream_t stream) {
  (void)in_sizes; (void)n_in; (void)d_ws; (void)ws_size; (void)out_size;
  garch_mfma8_kernel<<<dim3(B_ / 16), dim3(256), 0, stream>>>(
      (const float*)d_in[0],  // obs_sequence [B,S,OBS]
      (const float*)d_in[1],  // prev_actions [B,S,NINS]
      (const float*)d_in[2],  // W_in [H, OBS+NINS]
      (const float*)d_in[3],  // b_in [H]
      (const float*)d_in[4],  // rms_w [NBLK,H]
      (const float*)d_in[5],  // W_ih [NBLK,4H,H]
      (const float*)d_in[6],  // W_hh [NBLK,4H,H]
      (const float*)d_in[7],  // b_ih [NBLK,4H]
      (const float*)d_in[8],  // b_hh [NBLK,4H]
      (const float*)d_in[9],  // head_w [NINS,H]
      (const float*)d_in[10], // head_b [NINS]
      (float*)d_out);
}